// Round 14
// baseline (63.812 us; speedup 1.0000x reference)
//
#include <hip/hip_runtime.h>

// DecisionTreePolicy — complete binary tree, depth 15 (32767 nodes).
// Internal 0..16382 (children 2i+1/2i+2), leaves 16383..32766 -> exactly 14
// decisions from root; out[b] = leaf_logits[leaf(b)].
//
// History: R1/R2 gathers 84us. R4 LDS-stream 68.5. R7 depth-2 barrier-synced
// 67.2. R11 2 waves/SIMD partitioned rows 64.5. R13 barrier-free DMA 62.4
// (best): per-wave depth-1 prefetch -> only 32 KB/CU outstanding reads, but
// Little's law needs ~45 KB at ~1.8us loaded latency -> latency-bound.
// R14: barrier-free + REGISTER-staged depth-4 pipeline. Four groups pfA-D
// (halves h..h+3, 4 KB each) always in flight as NT loads -> 96-128 KB/CU
// outstanding. Wave ds_writes its OWN 4 rows and traverses only those: no
// loop barriers at all; compiler orders same-wave LDS deps and inserts
// counted vmcnt waits. Epilogue split gather(h-2)/store(h-3) so the gather
// use-wait only retires >=2-period-old load groups.

#define N_INTERN  16383
#define N_FEAT    256
#define N_ACT     64
#define BATCH     262144
#define BLOCK     512
#define GRID      256
#define ROWS_PB   (BATCH / GRID)      // 1024 rows per block
#define HROWS     32                  // rows per half-tile (32 KB)
#define HALVES    (ROWS_PB / HROWS)   // 32
#define DEPTH     14

typedef float f32x4 __attribute__((ext_vector_type(4)));

__global__ __launch_bounds__(BLOCK, 1) void tree_policy_kernel(
    const float* __restrict__ obs,          // [BATCH][N_FEAT]
    const int*   __restrict__ features,     // [N_NODES]
    const float* __restrict__ thresholds,   // [N_NODES]
    const float* __restrict__ leaf_logits,  // [N_NODES][N_ACT]
    float*       __restrict__ out)          // [BATCH][N_ACT]
{
    __shared__ float         sthr [N_INTERN];        // 64 KB
    __shared__ unsigned char sfeat[N_INTERN];        // 16 KB
    __shared__ __align__(16) f32x4 buf[2][HROWS * N_FEAT / 4];  // 2 x 32 KB -> 144 KB

    const int tid  = threadIdx.x;
    const int lane = tid & 63;
    const int wave = tid >> 6;                // 0..7; 2 waves/SIMD
    const long rowBase = (long)blockIdx.x * ROWS_PB;

    // ---- tree -> LDS (cooperative, one-time) ----
    for (int i = tid; i < N_INTERN; i += BLOCK) {
        sthr[i]  = thresholds[i];
        sfeat[i] = (unsigned char)features[i];
    }
    const float thr_root  = thresholds[0];
    const int   feat_root = features[0];

    // Row ownership: wave w stages AND traverses rows [4w, 4w+4) of each half.
    const int myrow_id = (wave << 2) | (lane >> 4);   // 0..31
    const int chunk    = lane & 15;                   // this lane's f32x4 chunk

    // Load group for half h: pf[k] = f32x4 #lane of row (4w+k). Each row's 64
    // lanes read 1 KB contiguous (perfectly coalesced); NT keeps the stream
    // from polluting L2/L3 (protects leaf_logits residency).
    const f32x4* gsrc = (const f32x4*)obs;    // global index: row*64 + j
    auto ldgrp = [&](int h, f32x4 (&pf)[4]) {
#pragma unroll
        for (int k = 0; k < 4; ++k) {
            const long row = rowBase + (long)h * HROWS + (wave << 2) + k;
            pf[k] = __builtin_nontemporal_load(&gsrc[row * 64 + lane]);
        }
    };

    // ---- prologue: fill the depth-4 pipe ----
    f32x4 pfA[4], pfB[4], pfC[4], pfD[4];
    ldgrp(0, pfA); ldgrp(1, pfB); ldgrp(2, pfC); ldgrp(3, pfD);

    asm volatile("s_waitcnt lgkmcnt(0)" ::: "memory");  // tree ds_writes done
    __builtin_amdgcn_s_barrier();        // the ONLY barrier: tree visible
    __builtin_amdgcn_sched_barrier(0);   // (pf loads stay in flight across it)

    // Child-prefetch traversal: obs lookup (fcur in register) runs parallel
    // to children's thr/feat reads -> one dependent LDS round-trip per level.
    auto traverse = [&](int h) -> int {
        const float* myrow = (const float*)&buf[h & 1][myrow_id * 64];
        int node = 0; float tcur = thr_root; int fcur = feat_root;
#pragma unroll
        for (int d = 0; d < DEPTH - 1; ++d) {
            const float x   = myrow[fcur];
            const int   c   = 2 * node + 1;
            const float tl  = sthr[c];
            const float trr = sthr[c + 1];
            const int   fl  = sfeat[c];
            const int   fr  = sfeat[c + 1];
            const bool  L   = (x <= tcur);          // reference NaN semantics
            node = L ? c : c + 1;
            tcur = L ? tl : trr;
            fcur = L ? fl : fr;
        }
        const float x = myrow[fcur];                 // last level: children = leaves
        return 2 * node + ((x <= tcur) ? 1 : 2);
    };

    int   n1 = 0, n2 = 0;               // node(h-1), node(h-2)
    f32x4 v_old = {0.f, 0.f, 0.f, 0.f}; // gathered leaf row for half h-3

    auto body = [&](int h, f32x4 (&pf)[4]) {
        // ph1: issue epilogue gather for half h-2 (oldest VMEM this iter)
        f32x4 v_new = v_old;
        if (h >= 2)
            v_new = *(const f32x4*)(leaf_logits + (size_t)n2 * N_ACT + chunk * 4);
        __builtin_amdgcn_sched_barrier(0);
        // ph2: epilogue store for half h-3 (its gather is 1 iter old; the
        // use-wait only retires load groups >= 2 periods old)
        if (h >= 3) {
            const long orow = rowBase + (long)(h - 3) * HROWS + myrow_id;
            __builtin_nontemporal_store(v_old, (f32x4*)(out + orow * N_ACT + chunk * 4));
        }
        __builtin_amdgcn_sched_barrier(0);
        // ph3: regs -> LDS, own rows only (compiler inserts counted vmcnt
        // wait for loads(h); no barrier needed — wave-private)
#pragma unroll
        for (int k = 0; k < 4; ++k)
            buf[h & 1][((wave << 2) + k) * 64 + lane] = pf[k];
        // ph4: re-issue this register group for half h+4
        if (h + 4 < HALVES) ldgrp(h + 4, pf);
        __builtin_amdgcn_sched_barrier(0);
        // ph5: traverse (compiler orders same-wave ds_write -> ds_read)
        const int nd = traverse(h);
        n2 = n1; n1 = nd;
        v_old = v_new;
    };

    for (int hh = 0; hh < HALVES; hh += 4) {
        body(hh + 0, pfA);
        body(hh + 1, pfB);
        body(hh + 2, pfC);
        body(hh + 3, pfD);
    }

    // ---- drain: v_old = v(29); n1 = node(31), n2 = node(30) ----
    {
        const long o29 = rowBase + 29L * HROWS + myrow_id;
        __builtin_nontemporal_store(v_old, (f32x4*)(out + o29 * N_ACT + chunk * 4));
        const f32x4 v30 = *(const f32x4*)(leaf_logits + (size_t)n2 * N_ACT + chunk * 4);
        const long o30 = rowBase + 30L * HROWS + myrow_id;
        __builtin_nontemporal_store(v30, (f32x4*)(out + o30 * N_ACT + chunk * 4));
        const f32x4 v31 = *(const f32x4*)(leaf_logits + (size_t)n1 * N_ACT + chunk * 4);
        const long o31 = rowBase + 31L * HROWS + myrow_id;
        __builtin_nontemporal_store(v31, (f32x4*)(out + o31 * N_ACT + chunk * 4));
    }
}

extern "C" void kernel_launch(void* const* d_in, const int* in_sizes, int n_in,
                              void* d_out, int out_size, void* d_ws, size_t ws_size,
                              hipStream_t stream) {
    const float* obs         = (const float*)d_in[0];
    const int*   features    = (const int*)  d_in[1];
    const float* thresholds  = (const float*)d_in[2];
    // d_in[3]/d_in[4] (children) unused: tree is complete by construction.
    const float* leaf_logits = (const float*)d_in[5];
    float*       out         = (float*)d_out;

    tree_policy_kernel<<<dim3(GRID), dim3(BLOCK), 0, stream>>>(
        obs, features, thresholds, leaf_logits, out);
}

// Round 15
// 60.845 us; speedup vs baseline: 1.0488x; 1.0488x over previous
//
#include <hip/hip_runtime.h>

// DecisionTreePolicy — complete binary tree, depth 15 (32767 nodes).
// Internal 0..16382 (children 2i+1/2i+2), leaves 16383..32766 -> exactly 14
// decisions from root; out[b] = leaf_logits[leaf(b)].
//
// History: R1/R2 gathers 84us. R4 LDS-stream 68.5. R7 counted-vmcnt 67.2.
// R11 2 waves/SIMD partitioned rows 64.5. R13 barrier-free per-wave DMA 62.4
// (best). R14 reg-staged depth-4 63.8 — the leaf-gather's wait drains older
// prefetch groups, so depth collapses to 1; outstanding-bytes falsified.
// R15 = R13 + two fixes: (1) output store moved AFTER traverse, so the leaf
// gather's ~250-cycle latency hides under the traversal instead of stalling
// serially every half; (2) LDS obs rows padded to 1040 B (260 f32) — wave's
// 4 rows land on banks f, f+4, f+8, f+12: converged-level reads conflict-free
// (was 4-way). DMA per row stays legal: 1 KB contiguous dest per instruction.

#define N_INTERN  16383
#define N_FEAT    256
#define N_ACT     64
#define BATCH     262144
#define BLOCK     512
#define GRID      256
#define ROWS_PB   (BATCH / GRID)      // 1024 rows per block
#define HROWS     32                  // rows per half-tile
#define HALVES    (ROWS_PB / HROWS)   // 32
#define DEPTH     14
#define RPAD      260                 // padded row stride in floats (1040 B)

typedef float f32x4 __attribute__((ext_vector_type(4)));
typedef __attribute__((address_space(3))) void        lds_void_t;
typedef const __attribute__((address_space(1))) void  glob_cvoid_t;

__device__ __forceinline__ void gload16(const void* g, void* l) {
    // async global->LDS DMA: per-lane global addr, wave-uniform LDS base,
    // HW writes lds_base + lane*16 (1 KB per instruction per wave).
    __builtin_amdgcn_global_load_lds((glob_cvoid_t*)g, (lds_void_t*)l, 16, 0, 0);
}

__global__ __launch_bounds__(BLOCK, 1) void tree_policy_kernel(
    const float* __restrict__ obs,          // [BATCH][N_FEAT]
    const int*   __restrict__ features,     // [N_NODES]
    const float* __restrict__ thresholds,   // [N_NODES]
    const float* __restrict__ leaf_logits,  // [N_NODES][N_ACT]
    float*       __restrict__ out)          // [BATCH][N_ACT]
{
    __shared__ float         sthr [N_INTERN];        // 64 KB
    __shared__ unsigned char sfeat[N_INTERN];        // 16 KB
    __shared__ __align__(16) float buf[2][HROWS * RPAD];  // 2 x 33.3 KB -> 146.6 KB

    const int tid  = threadIdx.x;
    const int lane = tid & 63;
    const int wave = tid >> 6;                // 0..7; 2 waves/SIMD
    const long rowBase = (long)blockIdx.x * ROWS_PB;

    // ---- tree -> LDS (cooperative, one-time) ----
    for (int i = tid; i < N_INTERN; i += BLOCK) {
        sthr[i]  = thresholds[i];
        sfeat[i] = (unsigned char)features[i];
    }
    const float thr_root  = thresholds[0];
    const int   feat_root = features[0];

    // Row ownership: wave w stages AND traverses rows [4w, 4w+4) of each half.
    const int myrow_id = (wave << 2) | (lane >> 4);   // 0..31
    const int chunk    = lane & 15;                   // this lane's f32x4 chunk

    // Per-wave DMA of its own 4 rows of half h (4 x 1KB; padded row stride).
    auto dma = [&](int h) {
        const float* g = obs + (rowBase + (long)h * HROWS + (wave << 2)) * N_FEAT + lane * 4;
        char* l = (char*)&buf[h & 1][(wave << 2) * RPAD];
#pragma unroll
        for (int k = 0; k < 4; ++k)
            gload16(g + k * N_FEAT, l + k * (RPAD * 4));
    };

    // Child-prefetch traversal: obs lookup (fcur in register) runs parallel
    // to children's thr/feat reads -> one dependent LDS round-trip per level.
    auto traverse = [&](int h) -> int {
        const float* myrow = &buf[h & 1][myrow_id * RPAD];
        int node = 0; float tcur = thr_root; int fcur = feat_root;
#pragma unroll
        for (int d = 0; d < DEPTH - 1; ++d) {
            const float x   = myrow[fcur];
            const int   c   = 2 * node + 1;
            const float tl  = sthr[c];
            const float trr = sthr[c + 1];
            const int   fl  = sfeat[c];
            const int   fr  = sfeat[c + 1];
            const bool  L   = (x <= tcur);          // reference NaN semantics
            node = L ? c : c + 1;
            tcur = L ? tl : trr;
            fcur = L ? fl : fr;
        }
        const float x = myrow[fcur];                 // last level: children = leaves
        return 2 * node + ((x <= tcur) ? 1 : 2);
    };

    // ---- prologue ----
    dma(0);
    asm volatile("s_waitcnt vmcnt(0) lgkmcnt(0)" ::: "memory");
    __builtin_amdgcn_s_barrier();        // the ONLY barrier: tree visible to all
    dma(1);
    __builtin_amdgcn_sched_barrier(0);
    int node_prev = traverse(0);

    for (int h = 1; h < HALVES; ++h) {
        // Own-wave wait: DMA(h) landed (issued a full period ago). h>=2: allow
        // 1 outstanding = previous output store (never drained in-loop).
        if (h == 1) asm volatile("s_waitcnt vmcnt(0)" ::: "memory");
        else        asm volatile("s_waitcnt vmcnt(1)" ::: "memory");
        __builtin_amdgcn_sched_barrier(0);
        // G(h-1): leaf gather issued now, consumed after traverse — its
        // latency hides under the traversal; wait leaves DMA(h+1) flying.
        const f32x4 v = *(const f32x4*)(leaf_logits + (size_t)node_prev * N_ACT + chunk * 4);
        __builtin_amdgcn_sched_barrier(0);
        if (h + 1 < HALVES) {
            dma(h + 1);
            __builtin_amdgcn_sched_barrier(0);
        }
        const int node_cur = traverse(h);            // LDS-only, ~0.8us
        __builtin_amdgcn_sched_barrier(0);
        // S(h-1): store after traverse; compiler's wait-for-gather is free now.
        const long orow = rowBase + (long)(h - 1) * HROWS + myrow_id;
        __builtin_nontemporal_store(v, (f32x4*)(out + orow * N_ACT + chunk * 4));
        __builtin_amdgcn_sched_barrier(0);
        node_prev = node_cur;
    }

    // final epilogue (half HALVES-1)
    const f32x4 v = *(const f32x4*)(leaf_logits + (size_t)node_prev * N_ACT + chunk * 4);
    const long orow = rowBase + (long)(HALVES - 1) * HROWS + myrow_id;
    __builtin_nontemporal_store(v, (f32x4*)(out + orow * N_ACT + chunk * 4));
}

extern "C" void kernel_launch(void* const* d_in, const int* in_sizes, int n_in,
                              void* d_out, int out_size, void* d_ws, size_t ws_size,
                              hipStream_t stream) {
    const float* obs         = (const float*)d_in[0];
    const int*   features    = (const int*)  d_in[1];
    const float* thresholds  = (const float*)d_in[2];
    // d_in[3]/d_in[4] (children) unused: tree is complete by construction.
    const float* leaf_logits = (const float*)d_in[5];
    float*       out         = (float*)d_out;

    tree_policy_kernel<<<dim3(GRID), dim3(BLOCK), 0, stream>>>(
        obs, features, thresholds, leaf_logits, out);
}